// Round 4
// baseline (4398.938 us; speedup 1.0000x reference)
//
#include <hip/hip_runtime.h>
#include <cmath>

// ---------------------------------------------------------------------------
// 2-layer LSTM, T=256 B=64 D=H=1024, ONE persistent kernel, NO global barrier,
// NO contended atomics (round-4: per-producer flag words, wave-parallel check).
//
//  - h1/h2 state in never-reused ring buffers (one 128 KB slab per timestep).
//    Readers use PLAIN CACHED loads (no address reuse -> no stale L2 copies);
//    writers use relaxed agent-scope 4B atomic stores (write-through to LLC).
//  - Readiness: flagX[producer][wave 0..3] = number of completed steps
//    (monotone). Producer wave stores its own word after draining its h
//    stores (vmcnt(0)) -> zero same-address contention, no RMWs at all.
//    Consumer wave checks all 512 words with 2x global_load_dwordx4 sc0 sc1
//    per lane + __all reduce. All h-consuming waves poll directly.
//
// Layouts (unchanged, verified):
//  packed gate col p = h*4 + g   (g: 0=i,1=j,2=f,3=o ; orig col = g*1024+h)
//  A-pack (64 x K):  AP[mt][kt][lane][j] = A[mt*16 + (lane&15)][kt*32 + (lane>>4)*8 + j]
//  B-pack (K x G):   WP[nt][kt][lane][j] = W[kt*32 + (lane>>4)*8 + j][origcol(nt*16 + (lane&15))]
//  MFMA 16x16x32 f16: D[row=(lane>>4)*4+r][col=lane&15]
// ---------------------------------------------------------------------------

typedef _Float16 half8 __attribute__((ext_vector_type(8)));
typedef float f32x4 __attribute__((ext_vector_type(4)));
typedef unsigned int uint4v __attribute__((ext_vector_type(4)));

constexpr int Tt = 256, Gg = 4096;
constexpr size_t HPACK = 65536;            // halves in one 64x1024 A-pack slab
constexpr int NBLK = 256;
constexpr unsigned WLDS_BYTES = 131072;    // 2 nt x 64 kt x 64 lane x 8 halves x 2B
constexpr unsigned ZP_FLOATS = 8 * 16 * 17;          // [mt*2+nl][16][17] padded
constexpr unsigned HSTAGE_BYTES = 64 * 8 * 2;        // 1 KiB h staging
constexpr unsigned SMEM_BYTES = WLDS_BYTES + ZP_FLOATS * 4 + HSTAGE_BYTES;

__device__ __forceinline__ float sigmoidf_(float x) { return 1.f / (1.f + expf(-x)); }

// ---- pack W (fp32 [2048][4096]) -> full-K fp16 B-pack ----------------------
__global__ void pack_w_kernel(const float* __restrict__ W0, const float* __restrict__ W1,
                              _Float16* __restrict__ WP0, _Float16* __restrict__ WP1) {
    int idx = blockIdx.x * 256 + threadIdx.x;      // [0, 2^20)
    const float* src = blockIdx.y ? W1 : W0;
    _Float16* dst = blockIdx.y ? WP1 : WP0;
    int lane = idx & 63;
    int kt = (idx >> 6) & 63;
    int nt = idx >> 12;
    int p = nt * 16 + (lane & 15);
    int col = (p & 3) * 1024 + (p >> 2);
    int kbase = kt * 32 + (lane >> 4) * 8;
    half8 v;
#pragma unroll
    for (int j = 0; j < 8; ++j) v[j] = (_Float16)src[(size_t)(kbase + j) * Gg + col];
    *reinterpret_cast<half8*>(dst + (size_t)idx * 8) = v;
}

__global__ void pack_bias_kernel(const float* __restrict__ b0, const float* __restrict__ b1,
                                 float* __restrict__ bp0, float* __restrict__ bp1) {
    int idx = blockIdx.x * 256 + threadIdx.x;      // [0, 8192)
    int l = idx >> 12, p = idx & 4095;
    int col = (p & 3) * 1024 + (p >> 2);
    (l ? bp1 : bp0)[p] = (l ? b1 : b0)[col];
}

// ---- pack X: fp32 [16384][1024] -> fp16 A-pack -----------------------------
__global__ void pack_a_kernel(const float* __restrict__ X, _Float16* __restrict__ XP) {
    int idx = blockIdx.x * 256 + threadIdx.x;      // [0, 1024*32*64)
    int lane = idx & 63;
    int kt = (idx >> 6) & 31;
    int mt = idx >> 11;
    int m = mt * 16 + (lane & 15);
    int kbase = kt * 32 + (lane >> 4) * 8;
    const float* srow = X + (size_t)m * 1024 + kbase;
    half8 v;
#pragma unroll
    for (int j = 0; j < 8; ++j) v[j] = (_Float16)srow[j];
    *reinterpret_cast<half8*>(XP + (size_t)idx * 8) = v;
}

// ---- wave-parallel readiness check -----------------------------------------
// flags: 128 producers x 4 subflag words (16B each, contiguous 2 KB).
// Lane L checks producers L and L+64. Done when all 512 words >= tgt.
__device__ __forceinline__ void wait_flags(const unsigned* flags, unsigned tgt) {
    int lane = threadIdx.x & 63;
    const unsigned* p0 = flags + (size_t)lane * 4;
    const unsigned* p1 = flags + (size_t)(lane + 64) * 4;
    unsigned spins = 0;
    for (;;) {
        uint4v f0, f1;
        asm volatile("global_load_dwordx4 %0, %2, off sc0 sc1\n\t"
                     "global_load_dwordx4 %1, %3, off sc0 sc1"
                     : "=v"(f0), "=v"(f1) : "v"(p0), "v"(p1));
        asm volatile("s_waitcnt vmcnt(0)" ::: "memory");
        bool ok = f0[0] >= tgt && f0[1] >= tgt && f0[2] >= tgt && f0[3] >= tgt &&
                  f1[0] >= tgt && f1[1] >= tgt && f1[2] >= tgt && f1[3] >= tgt;
        if (__all(ok)) break;
        __builtin_amdgcn_s_sleep(1);
        if (++spins > (1u << 18)) break;   // safety bail: never hang the harness
    }
    asm volatile("" ::: "memory");
}

struct FArgs {
    const _Float16* XP;
    const _Float16* WP0;
    const _Float16* WP1;
    const float* bp0;
    const float* bp1;
    _Float16* h1r;     // ring: (Tt+1) slabs of HPACK halves; slab j holds h1[j-1]
    _Float16* h2r;     // ring: (Tt+1) slabs
    unsigned* h1f;     // subflags: [128 producers][4 waves]
    unsigned* h2f;
    float* out;
};

__global__ __launch_bounds__(1024, 4) void lstm_fused(FArgs a) {
    extern __shared__ char smem[];
    _Float16* wlds = (_Float16*)smem;                          // 128 KB weights
    float* zp = (float*)(smem + WLDS_BYTES);                   // [8][16][17] f32
    _Float16* hstage = (_Float16*)(smem + WLDS_BYTES + ZP_FLOATS * 4);   // [64][8]

    const int tid = threadIdx.x;
    const int layer = blockIdx.x >> 7;     // 0 or 1
    const int cg = blockIdx.x & 127;       // colgroup: packed cols [cg*32, cg*32+32)

    // ---- stage this block's weight slice (2 n-tiles, contiguous in B-pack) ----
    const _Float16* wsrc = (layer ? a.WP1 : a.WP0) + (size_t)cg * 65536;
    for (int i = tid; i < 8192; i += 1024)
        ((half8*)wlds)[i] = ((const half8*)wsrc)[i];
    for (int i = tid; i < (int)ZP_FLOATS; i += 1024) zp[i] = 0.f;

    // ---- per-gate-thread persistent state ----
    float creg = 0.f;
    float bias4[4] = {0.f, 0.f, 0.f, 0.f};
    if (tid < 512) {
        int hl = tid & 7;
        const float* bp = layer ? a.bp1 : a.bp0;
#pragma unroll
        for (int g = 0; g < 4; ++g) bias4[g] = bp[cg * 32 + hl * 4 + g];
    }
    __syncthreads();

    const int lane = tid & 63, wv = tid >> 6;
    const int mt = wv & 3, kq = wv >> 2;           // 4 m-tiles x 4 K-quarters
    const int r0 = (lane >> 4) * 4, ccc = lane & 15;
    const int ktL = (kq & 1) * 16;                 // kt offset within the 32-kt source slab

    for (int t = 0; t < Tt; ++t) {
        // ---- phase 0: per-wave readiness (no scouts, no RMWs) ----
        if (layer == 0) {
            if (kq >= 2 && t > 0) wait_flags(a.h1f, (unsigned)t);        // h1[t-1]
        } else {
            if (kq < 2)           wait_flags(a.h1f, (unsigned)(t + 1));  // h1[t]
            else if (t > 0)       wait_flags(a.h2f, (unsigned)t);        // h2[t-1]
        }

        // ---- phase 1: GEMM quarter (plain cached loads; ring => no staleness) ----
        const _Float16* srcA;
        if (layer == 0)
            srcA = (kq < 2) ? (a.XP + (size_t)t * HPACK) : (a.h1r + (size_t)t * HPACK);
        else
            srcA = (kq < 2) ? (a.h1r + (size_t)(t + 1) * HPACK) : (a.h2r + (size_t)t * HPACK);

        const half8* ap = (const half8*)srcA + ((size_t)mt * 32 + ktL) * 64 + lane;
        const half8* bq0 = (const half8*)wlds + ((size_t)(0 * 64 + kq * 16)) * 64 + lane;
        const half8* bq1 = (const half8*)wlds + ((size_t)(1 * 64 + kq * 16)) * 64 + lane;
        f32x4 ac0 = {0.f, 0.f, 0.f, 0.f}, ac1 = {0.f, 0.f, 0.f, 0.f};
#pragma unroll
        for (int i = 0; i < 16; ++i) {
            half8 av = ap[i * 64];
            ac0 = __builtin_amdgcn_mfma_f32_16x16x32_f16(av, bq0[i * 64], ac0, 0, 0, 0);
            ac1 = __builtin_amdgcn_mfma_f32_16x16x32_f16(av, bq1[i * 64], ac1, 0, 0, 0);
        }
#pragma unroll
        for (int r = 0; r < 4; ++r) {
            atomicAdd(&zp[((mt * 2 + 0) * 16 + r0 + r) * 17 + ccc], ac0[r]);
            atomicAdd(&zp[((mt * 2 + 1) * 16 + r0 + r) * 17 + ccc], ac1[r]);
        }
        __syncthreads();

        // ---- phase 2: gates ----
        if (tid < 512) {
            int b = tid >> 3, hl = tid & 7;
            float z[4];
#pragma unroll
            for (int g = 0; g < 4; ++g) {
                int c = hl * 4 + g;
                z[g] = zp[(((b >> 4) * 2 + (c >> 4)) * 16 + (b & 15)) * 17 + (c & 15)] + bias4[g];
            }
            float cn = creg * sigmoidf_(z[2] + 1.0f) + sigmoidf_(z[0]) * tanhf(z[1]);
            float hn = tanhf(cn) * sigmoidf_(z[3]);
            creg = cn;
            hstage[b * 8 + hl] = (_Float16)hn;
            if (layer) a.out[(size_t)t * 65536 + (size_t)b * 1024 + (cg * 8 + hl)] = hn;
        }
        __syncthreads();

        // ---- phase 3: publish h slab; each storing wave drains + signals ----
        if (tid < 256) {
            int b = tid >> 2, pr = tid & 3;
            unsigned lo = (unsigned)__builtin_bit_cast(unsigned short, hstage[b * 8 + 2 * pr]);
            unsigned hi = (unsigned)__builtin_bit_cast(unsigned short, hstage[b * 8 + 2 * pr + 1]);
            unsigned val = lo | (hi << 16);
            _Float16* hdst = (layer ? a.h2r : a.h1r) + (size_t)(t + 1) * HPACK;
            size_t dw = (((size_t)(b >> 4) * 32 + (cg >> 2)) * 64 + (size_t)(cg & 3) * 16 + (b & 15)) * 4 + pr;
            __hip_atomic_store((unsigned*)hdst + dw, val, __ATOMIC_RELAXED, __HIP_MEMORY_SCOPE_AGENT);
            asm volatile("s_waitcnt vmcnt(0)" ::: "memory");   // own stores reached LLC
            __builtin_amdgcn_sched_barrier(0);
            if ((tid & 63) == 0) {
                unsigned* f = (layer ? a.h2f : a.h1f) + (size_t)cg * 4 + wv;
                __hip_atomic_store(f, (unsigned)(t + 1), __ATOMIC_RELAXED, __HIP_MEMORY_SCOPE_AGENT);
            }
        }
        for (int i = tid; i < (int)ZP_FLOATS; i += 1024) zp[i] = 0.f;
        __syncthreads();   // zp zeroed before next step's atomicAdds
    }
}

// ---------------------------------------------------------------------------
extern "C" void kernel_launch(void* const* d_in, const int* in_sizes, int n_in,
                              void* d_out, int out_size, void* d_ws, size_t ws_size,
                              hipStream_t stream) {
    const float* X  = (const float*)d_in[0];
    const float* W0 = (const float*)d_in[1];
    const float* b0 = (const float*)d_in[2];
    const float* W1 = (const float*)d_in[3];
    const float* b1 = (const float*)d_in[4];
    float* out = (float*)d_out;

    char* ws = (char*)d_ws;
    size_t off = 0;
    auto take = [&](size_t n) -> void* {
        void* r = ws + off;
        off += (n + 255) & ~(size_t)255;
        return r;
    };

    const size_t WPB = (size_t)2048 * Gg * 2;            // 16 MiB per packed W
    _Float16* WP0 = (_Float16*)take(WPB);
    _Float16* WP1 = (_Float16*)take(WPB);
    float* bp0 = (float*)take(Gg * 4);
    float* bp1 = (float*)take(Gg * 4);
    const size_t APB = (size_t)Tt * 64 * 1024 * 2;       // 32 MiB X A-pack
    _Float16* XP = (_Float16*)take(APB);
    const size_t RINGB = (size_t)(Tt + 1) * HPACK * 2;   // ~33.6 MiB per ring
    _Float16* h1r = (_Float16*)take(RINGB);
    _Float16* h2r = (_Float16*)take(RINGB);
    const size_t FLAGB = 128 * 4 * 4;                    // 2 KiB per flag array
    unsigned* h1f = (unsigned*)take(FLAGB);
    unsigned* h2f = (unsigned*)take(FLAGB);

    hipMemsetAsync(h1r, 0, HPACK * 2, stream);           // initial h slabs (t=-1)
    hipMemsetAsync(h2r, 0, HPACK * 2, stream);
    hipMemsetAsync(h1f, 0, FLAGB, stream);
    hipMemsetAsync(h2f, 0, FLAGB, stream);

    pack_w_kernel<<<dim3(4096, 2), 256, 0, stream>>>(W0, W1, WP0, WP1);
    pack_bias_kernel<<<32, 256, 0, stream>>>(b0, b1, bp0, bp1);
    pack_a_kernel<<<8192, 256, 0, stream>>>(X, XP);

    hipFuncSetAttribute((const void*)lstm_fused,
                        hipFuncAttributeMaxDynamicSharedMemorySize, SMEM_BYTES);

    FArgs fa{XP, WP0, WP1, bp0, bp1, h1r, h2r, h1f, h2f, out};
    void* kp[] = {&fa};
    hipError_t e = hipLaunchCooperativeKernel((const void*)lstm_fused, dim3(NBLK), dim3(1024),
                                              kp, SMEM_BYTES, stream);
    if (e != hipSuccess) {
        lstm_fused<<<dim3(NBLK), dim3(1024), SMEM_BYTES, stream>>>(fa);
    }
    (void)in_sizes; (void)n_in; (void)out_size; (void)ws_size;
}